// Round 2
// baseline (64.209 us; speedup 1.0000x reference)
//
#include <hip/hip_runtime.h>

// RPQWeight gather:
//   indices:   (H=32, C=16384) int32, values in [0, 256)
//   codebooks: (H=32, NC=256, D=128) float32
//   out:       (C=16384, H*D=4096) float32
//   out[c, h*D + d] = codebooks[h, indices[h,c], d]
//
// R2: compile-time trip count (32 iters/thread), 8-way batched unroll
// (8 independent idx->gather->store chains in flight), nontemporal
// stores so the 268 MB output stream doesn't evict the 4 MiB codebooks
// from L2. Stores remain perfectly coalesced (lane i -> float4 #i).

#define RPQ_H  32
#define RPQ_C  16384
#define RPQ_D  128
#define RPQ_NC 256

#define BLOCK   256
#define GRID    2048
#define NTHREAD (BLOCK * GRID)                    // 524288
#define TOTAL4  ((unsigned)RPQ_C * (RPQ_H * RPQ_D / 4))  // 16777216 float4
#define ITERS   (TOTAL4 / NTHREAD)                // 32
#define CSTEP   (NTHREAD >> 10)                   // c advances 512 per iter

typedef float f4 __attribute__((ext_vector_type(4)));

__global__ __launch_bounds__(BLOCK) void rpq_gather_kernel(
        const int* __restrict__ indices,
        const float* __restrict__ codebooks,
        float* __restrict__ out) {
    const f4* __restrict__ cb = reinterpret_cast<const f4*>(codebooks);
    f4* __restrict__ o = reinterpret_cast<f4*>(out);

    const unsigned tid = blockIdx.x * BLOCK + threadIdx.x;

    // Per-thread invariants: stride between iters is 2^19 float4, a
    // multiple of 1024 (= float4 per output row), so h and d4 are fixed.
    const unsigned rem = tid & 1023u;   // position within output row
    const unsigned h   = rem >> 5;      // codebook id
    const unsigned d4  = rem & 31u;     // float4 within the 128-f row
    const unsigned c0  = tid >> 10;     // starting output row

    const int* __restrict__ idxp = indices + h * RPQ_C + c0;
    const f4*  __restrict__ cbh  = cb + ((h << 8) * 32u) + d4;
    f4* __restrict__ op = o + tid;

#pragma unroll
    for (int it = 0; it < ITERS; it += 8) {
        int idx[8];
#pragma unroll
        for (int k = 0; k < 8; ++k)
            idx[k] = idxp[(unsigned)(it + k) * CSTEP];

        f4 val[8];
#pragma unroll
        for (int k = 0; k < 8; ++k)
            val[k] = cbh[(unsigned)idx[k] * 32u];

#pragma unroll
        for (int k = 0; k < 8; ++k)
            __builtin_nontemporal_store(val[k],
                op + (unsigned)(it + k) * (unsigned)NTHREAD);
    }
}

extern "C" void kernel_launch(void* const* d_in, const int* in_sizes, int n_in,
                              void* d_out, int out_size, void* d_ws, size_t ws_size,
                              hipStream_t stream) {
    const int*   indices   = (const int*)d_in[0];
    const float* codebooks = (const float*)d_in[1];
    float*       out       = (float*)d_out;

    rpq_gather_kernel<<<GRID, BLOCK, 0, stream>>>(indices, codebooks, out);
}

// Round 3
// 54.736 us; speedup vs baseline: 1.1731x; 1.1731x over previous
//
#include <hip/hip_runtime.h>

// RPQWeight gather, LDS-staged codebook:
//   indices:   (H=32, C=16384) int32 in [0,256)
//   codebooks: (H=32, NC=256, D=128) float32
//   out[c, h*128+d] = codebooks[h, indices[h,c], d]   -> (16384, 4096) f32
//
// R3: each block owns one h and a 1024-row chunk of c. Stage the whole
// 128 KiB codebook slice + 4 KiB of indices in LDS; main loop has ZERO
// global reads (idx broadcast + conflict-free ds_read_b128 gather),
// so the 268 MB coalesced write stream runs at the pure-store ceiling
// without L2 read/write interference.

#define RPQ_H  32
#define RPQ_C  16384
#define RPQ_D  128
#define RPQ_NC 256

#define BLOCK        1024
#define CBLK_PER_H   16
#define ROWS_PER_BLK (RPQ_C / CBLK_PER_H)          // 1024
#define GRID         (RPQ_H * CBLK_PER_H)          // 512

#define CB_F4_PER_H  (RPQ_NC * RPQ_D / 4)          // 8192 float4 = 128 KiB
#define LDS_CB_BYTES (CB_F4_PER_H * 16)            // 131072
#define LDS_IDX_BYTES (ROWS_PER_BLK * 4)           // 4096
#define LDS_BYTES    (LDS_CB_BYTES + LDS_IDX_BYTES)

#define ROW_F4       (RPQ_H * RPQ_D / 4)           // 1024 float4 per out row

typedef float f4 __attribute__((ext_vector_type(4)));

__global__ __launch_bounds__(BLOCK) void rpq_lds_kernel(
        const int* __restrict__ indices,
        const float* __restrict__ codebooks,
        float* __restrict__ out) {
    extern __shared__ char smem[];
    f4*  lds_cb  = reinterpret_cast<f4*>(smem);
    int* lds_idx = reinterpret_cast<int*>(smem + LDS_CB_BYTES);

    const unsigned bid    = blockIdx.x;
    const unsigned h      = bid >> 4;          // 16 blocks per h
    const unsigned cblk   = bid & 15u;
    const unsigned c_base = cblk * ROWS_PER_BLK;
    const unsigned tid    = threadIdx.x;

    // Prologue: codebook slice h -> LDS (coalesced, 8 float4/thread)
    const f4* cb4 = reinterpret_cast<const f4*>(codebooks) + (size_t)h * CB_F4_PER_H;
#pragma unroll
    for (int k = 0; k < 8; ++k)
        lds_cb[tid + k * BLOCK] = cb4[tid + k * BLOCK];
    // This block's 1024 indices -> LDS
    lds_idx[tid] = indices[h * RPQ_C + c_base + tid];
    __syncthreads();

    // Main loop: thread -> (row r0 + 32*it, float4 column d4)
    const unsigned d4 = tid & 31u;             // float4 within the 128-f slice
    const unsigned r0 = tid >> 5;              // 0..31
    f4* o = reinterpret_cast<f4*>(out)
            + (size_t)(c_base + r0) * ROW_F4 + h * (RPQ_D / 4) + d4;

#pragma unroll 4
    for (int it = 0; it < ROWS_PER_BLK / 32; ++it) {
        const int idx = lds_idx[it * 32 + r0];             // LDS broadcast
        const f4  v   = lds_cb[(unsigned)idx * 32u + d4];  // conflict-free
        o[(size_t)it * 32u * ROW_F4] = v;                  // coalesced 512B/row
    }
}

extern "C" void kernel_launch(void* const* d_in, const int* in_sizes, int n_in,
                              void* d_out, int out_size, void* d_ws, size_t ws_size,
                              hipStream_t stream) {
    const int*   indices   = (const int*)d_in[0];
    const float* codebooks = (const float*)d_in[1];
    float*       out       = (float*)d_out;

    // >64 KiB dynamic LDS needs explicit opt-in (host-side attr set; not a
    // stream op, safe under graph capture; idempotent & deterministic).
    hipFuncSetAttribute((const void*)rpq_lds_kernel,
                        hipFuncAttributeMaxDynamicSharedMemorySize, LDS_BYTES);

    rpq_lds_kernel<<<GRID, BLOCK, LDS_BYTES, stream>>>(indices, codebooks, out);
}

// Round 4
// 47.715 us; speedup vs baseline: 1.3457x; 1.1472x over previous
//
#include <hip/hip_runtime.h>

// RPQWeight gather, LDS-staged codebook, single-round schedule:
//   indices:   (H=32, C=16384) int32 in [0,256)
//   codebooks: (H=32, NC=256, D=128) float32
//   out[c, h*128+d] = codebooks[h, indices[h,c], d]   -> (16384, 4096) f32
//
// R4: 256 blocks = exactly 1 per CU (LDS-capped at 1 block/CU anyway), so
// the staging prologue is paid exactly ONCE chip-wide, then the main loop
// is a pure coalesced 268 MB store stream with zero global reads.
// Each block: one h, 2048 output rows. LDS = 128 KiB codebook slice
// + 8 KiB indices = 136 KiB.

#define RPQ_H  32
#define RPQ_C  16384
#define RPQ_D  128
#define RPQ_NC 256

#define BLOCK        1024
#define CBLK_PER_H   8
#define ROWS_PER_BLK (RPQ_C / CBLK_PER_H)          // 2048
#define GRID         (RPQ_H * CBLK_PER_H)          // 256 = #CUs

#define CB_F4_PER_H   (RPQ_NC * RPQ_D / 4)         // 8192 float4 = 128 KiB
#define LDS_CB_BYTES  (CB_F4_PER_H * 16)           // 131072
#define LDS_IDX_BYTES (ROWS_PER_BLK * 4)           // 8192
#define LDS_BYTES     (LDS_CB_BYTES + LDS_IDX_BYTES)  // 139264 <= 160 KiB

#define ROW_F4       (RPQ_H * RPQ_D / 4)           // 1024 float4 per out row
#define ITERS        (ROWS_PER_BLK / 32)           // 64

typedef float f4 __attribute__((ext_vector_type(4)));

__global__ __launch_bounds__(BLOCK) void rpq_lds_kernel(
        const int* __restrict__ indices,
        const float* __restrict__ codebooks,
        float* __restrict__ out) {
    extern __shared__ char smem[];
    f4*  lds_cb  = reinterpret_cast<f4*>(smem);
    int* lds_idx = reinterpret_cast<int*>(smem + LDS_CB_BYTES);

    const unsigned bid    = blockIdx.x;
    const unsigned h      = bid >> 3;          // 8 blocks per h
    const unsigned cblk   = bid & 7u;
    const unsigned c_base = cblk * ROWS_PER_BLK;
    const unsigned tid    = threadIdx.x;

    // Prologue (once per CU): codebook slice h -> LDS, coalesced.
    const f4* cb4 = reinterpret_cast<const f4*>(codebooks) + (size_t)h * CB_F4_PER_H;
#pragma unroll
    for (int k = 0; k < 8; ++k)
        lds_cb[tid + k * BLOCK] = cb4[tid + k * BLOCK];
    // This block's 2048 indices -> LDS.
    lds_idx[tid]         = indices[h * RPQ_C + c_base + tid];
    lds_idx[tid + BLOCK] = indices[h * RPQ_C + c_base + tid + BLOCK];
    __syncthreads();

    // Main loop: thread -> (row r0 + 32*it, float4 column d4 of slice h).
    const unsigned d4 = tid & 31u;             // float4 within the 128-f slice
    const unsigned r0 = tid >> 5;              // 0..31
    f4* o = reinterpret_cast<f4*>(out)
            + (size_t)(c_base + r0) * ROW_F4 + h * (RPQ_D / 4) + d4;

#pragma unroll 8
    for (int it = 0; it < ITERS; ++it) {
        const int idx = lds_idx[it * 32 + r0];             // LDS broadcast
        const f4  v   = lds_cb[(unsigned)idx * 32u + d4];  // conflict-free
        o[(size_t)it * 32u * ROW_F4] = v;                  // coalesced
    }
}

extern "C" void kernel_launch(void* const* d_in, const int* in_sizes, int n_in,
                              void* d_out, int out_size, void* d_ws, size_t ws_size,
                              hipStream_t stream) {
    const int*   indices   = (const int*)d_in[0];
    const float* codebooks = (const float*)d_in[1];
    float*       out       = (float*)d_out;

    // >64 KiB dynamic LDS needs explicit opt-in (host-side attr, not a
    // stream op; graph-capture-safe, idempotent, deterministic).
    hipFuncSetAttribute((const void*)rpq_lds_kernel,
                        hipFuncAttributeMaxDynamicSharedMemorySize, LDS_BYTES);

    rpq_lds_kernel<<<GRID, BLOCK, LDS_BYTES, stream>>>(indices, codebooks, out);
}